// Round 11
// baseline (86.138 us; speedup 1.0000x reference)
//
#include <hip/hip_runtime.h>

#define HH 256
#define WW 512
#define NCIN 16
#define NCOUT 32
#define NB 4
#define KP 168     // Sl row stride in halfs (336 B)
#define WKP 168    // wtab row stride in halfs (pad zeroed through 167)
#define NPIX 64    // pixels per block

typedef _Float16 h2 __attribute__((ext_vector_type(2)));
typedef _Float16 half4 __attribute__((ext_vector_type(4)));
typedef _Float16 half8 __attribute__((ext_vector_type(8)));
typedef float f32x4 __attribute__((ext_vector_type(4)));

// ws layout
#define XT_OFF   0u                  // fp16 xt: 4*256*512*16 half = 16 MiB
#define XTAB_OFF 16777216u           // float2[256*9*512] = 9 MiB
#define WTAB_OFF (16777216u + 9437184u)          // half[32*168]
#define YTAB_OFF (16777216u + 9437184u + 16384u) // float4[256*9]
#define WS_NEED  (YTAB_OFF + 36864u)

// ---- precompute (merged): xtab (blocks 0..4607), wtab+ytab (blocks 4608..4637) ----
__global__ __launch_bounds__(256) void precompute_all(const float* __restrict__ w,
                                                      const float* __restrict__ grid,
                                                      float2* __restrict__ xtab,
                                                      _Float16* __restrict__ wtab,
                                                      float4* __restrict__ ytab) {
    const float2* g2 = reinterpret_cast<const float2*>(grid);
    if (blockIdx.x < 4608) {
        const int t = blockIdx.x * 256 + threadIdx.x;   // (r*9+tap)*512 + c
        const int c = t & (WW - 1);
        const int u = t >> 9;
        const int r = u / 9, tap = u - r * 9;
        const int kr = tap / 3, kc = tap - kr * 3;
        const float gx = g2[(size_t)(r * 3 + kr) * (WW * 3) + (c * 3 + kc)].x;
        const float ix = ((gx + 1.0f) * 0.5f) * (float)(WW - 1);
        const float x0f = floorf(ix);
        xtab[t] = make_float2(ix - x0f, __int_as_float((int)x0f));
        return;
    }
    const int t = (blockIdx.x - 4608) * 256 + threadIdx.x;
    if (t < NCOUT * WKP) {
        const int co = t / WKP, kk = t - co * WKP;
        float v = 0.0f;
        if (kk < 144) v = w[co * 144 + (kk & 15) * 9 + (kk >> 4)];
        wtab[t] = (_Float16)v;
    } else if (t < NCOUT * WKP + HH * 9) {
        const int u = t - NCOUT * WKP;
        const int r = u / 9, tap = u - r * 9;
        const int kr = tap / 3, kc = tap - kr * 3;
        const float gy = g2[(size_t)(r * 3 + kr) * (WW * 3) + kc].y;   // col 0 (gy col-indep)
        const float iy = ((gy + 1.0f) * 0.5f) * (float)(HH - 1);
        const float y0f = floorf(iy);
        const float fy = iy - y0f;
        const int y0 = (int)y0f, y1 = y0 + 1;
        float wy0 = 1.0f - fy, wy1 = fy;
        if (y0 < 0 || y0 > HH - 1) wy0 = 0.0f;
        if (y1 < 0 || y1 > HH - 1) wy1 = 0.0f;
        const int cy0 = min(max(y0, 0), HH - 1), cy1 = min(max(y1, 0), HH - 1);
        ytab[u] = make_float4(wy0, wy1, __int_as_float(cy0), __int_as_float(cy1));
    }
}

// ---- pre-pass: x (B,Cin,H,W) -> xh (B,H,W,Cin) fp16 ----
__global__ __launch_bounds__(256) void transpose_x_kernel(const float* __restrict__ x,
                                                          _Float16* __restrict__ xh) {
    const int lb = (blockIdx.x & 7) * 256 + (blockIdx.x >> 3);
    const int t = lb * 256 + threadIdx.x;
    const int c = t & (WW - 1);
    const int r = (t >> 9) & (HH - 1);
    const int b = t >> 17;
    const float* xp = x + ((size_t)(b * NCIN) * HH + r) * WW + c;
    half8 h0, h1;
#pragma unroll
    for (int ci = 0; ci < 8; ++ci)  h0[ci] = (_Float16)xp[(size_t)ci * (HH * WW)];
#pragma unroll
    for (int ci = 0; ci < 8; ++ci)  h1[ci] = (_Float16)xp[(size_t)(8 + ci) * (HH * WW)];
    half8* op = reinterpret_cast<half8*>(xh) + (size_t)t * 2;
    op[0] = h0;
    op[1] = h1;
}

// ---- fused sample+conv. Round-11: r10's load hoist was DEFEATED by the
// scheduler (VGPR_Count=40, not ~130). Pin the clusters with
// sched_barrier(0): {9 xtab loads} | {36 gathers} | {interp}. This is the
// real ILP experiment; arithmetic bit-identical to r9/r10.
__global__ __launch_bounds__(256, 3) void sphere_mfma_kernel(const _Float16* __restrict__ xh,
                                                             const float2* __restrict__ xtab,
                                                             const _Float16* __restrict__ wtab,
                                                             const float4* __restrict__ ytab,
                                                             const float* __restrict__ bias,
                                                             float* __restrict__ out) {
    __shared__ _Float16 Sl[NPIX * KP];   // [p][kk], kk=tap*16+ci, pad 144..159 zeroed
    const int tid = threadIdx.x, lane = tid & 63, wv = tid >> 6;
    const int col = lane & 15, g4 = lane >> 4;

    const int lb = ((blockIdx.x & 7) << 10) + (blockIdx.x >> 3);  // 8192 blocks, bijective
    const int pixbase = lb << 6;
    const int b    = pixbase >> 17;
    const int rimg = (pixbase >> 9) & (HH - 1);
    const int c0   = pixbase & (WW - 1);

    const int pl = lane >> 2, q = lane & 3;
    const int p  = wv * 16 + pl;

    if (tid < 128) {   // zero Sl pad kk 144..159
        const int pp = tid >> 1, j = tid & 1;
        half8 z = {0, 0, 0, 0, 0, 0, 0, 0};
        *reinterpret_cast<half8*>(&Sl[pp * KP + 144 + j * 8]) = z;
    }

    // ---- wave-uniform y-side data (scalar loads) ----
    float wy0s[9], wy1s[9];
    int Rb0[9], Rb1[9];
#pragma unroll
    for (int t = 0; t < 9; ++t) {
        const float4 y = ytab[rimg * 9 + t];
        wy0s[t] = y.x;
        wy1s[t] = y.y;
        Rb0[t] = (b * HH + __float_as_int(y.z)) << 11;   // half4-unit row base
        Rb1[t] = (b * HH + __float_as_int(y.w)) << 11;
    }

    // ---- cluster 1: issue ALL 9 x-side table loads ----
    const float2* xrow = xtab + (size_t)rimg * 9 * WW + (c0 + p);
    float2 f2s[9];
#pragma unroll
    for (int t = 0; t < 9; ++t) f2s[t] = xrow[t * WW];
    __builtin_amdgcn_sched_barrier(0);

    // ---- cluster 2: issue ALL 36 gathers (36 loads in flight per lane) ----
    const half4* x4 = reinterpret_cast<const half4*>(xh);
    half4 A00[9], A01[9], A10[9], A11[9];
#pragma unroll
    for (int t = 0; t < 9; ++t) {
        const int bq = (__float_as_int(f2s[t].y) << 2) + q;
        const int o0 = Rb0[t] + bq, o1 = Rb1[t] + bq;
        A00[t] = x4[o0];
        A01[t] = x4[o0 + 4];
        A10[t] = x4[o1];
        A11[t] = x4[o1 + 4];
    }
    __builtin_amdgcn_sched_barrier(0);

    // ---- cluster 3: interp (pk-fp16, identical arithmetic to r9/r10) ----
#pragma unroll
    for (int t = 0; t < 9; ++t) {
        const float fx = f2s[t].x;
        const float wx0 = 1.0f - fx;
        const float w00 = wx0 * wy0s[t], w01 = fx * wy0s[t];
        const float w10 = wx0 * wy1s[t], w11 = fx * wy1s[t];
        const h2 W00 = {(_Float16)w00, (_Float16)w00};
        const h2 W01 = {(_Float16)w01, (_Float16)w01};
        const h2 W10 = {(_Float16)w10, (_Float16)w10};
        const h2 W11 = {(_Float16)w11, (_Float16)w11};
        h2 lo = A00[t].lo * W00;
        lo += A01[t].lo * W01;
        lo += A10[t].lo * W10;
        lo += A11[t].lo * W11;
        h2 hi = A00[t].hi * W00;
        hi += A01[t].hi * W01;
        hi += A10[t].hi * W10;
        hi += A11[t].hi * W11;
        const half4 pk = {lo.x, lo.y, hi.x, hi.y};
        *reinterpret_cast<half4*>(&Sl[p * KP + t * 16 + q * 4]) = pk;
    }
    __builtin_amdgcn_sched_barrier(0);

    // ---- W fragments -> registers (after interp: lifetimes don't overlap A[]) ----
    half8 wA[5][2];
#pragma unroll
    for (int s = 0; s < 5; ++s)
#pragma unroll
        for (int m = 0; m < 2; ++m)
            wA[s][m] = *reinterpret_cast<const half8*>(wtab + (m * 16 + col) * WKP + s * 32 + g4 * 8);

    __syncthreads();

    // ---- MFMA: wave wv owns pixels [wv*16, wv*16+16), couts 0..31 ----
    f32x4 acc0 = {0.f, 0.f, 0.f, 0.f}, acc1 = {0.f, 0.f, 0.f, 0.f};
#pragma unroll
    for (int s = 0; s < 5; ++s) {
        const half8 bf = *reinterpret_cast<const half8*>(&Sl[(wv * 16 + col) * KP + s * 32 + g4 * 8]);
        acc0 = __builtin_amdgcn_mfma_f32_16x16x32_f16(wA[s][0], bf, acc0, 0, 0, 0);
        acc1 = __builtin_amdgcn_mfma_f32_16x16x32_f16(wA[s][1], bf, acc1, 0, 0, 0);
    }

    // ---- epilogue: C col=lane&15 (pixel), row=(lane>>4)*4+reg (cout) ----
    const int pix = c0 + wv * 16 + col;
    float* ob = out + (((size_t)(b * NCOUT) * HH + rimg) * WW) + pix;
#pragma unroll
    for (int m = 0; m < 2; ++m) {
        const f32x4 a = m ? acc1 : acc0;
#pragma unroll
        for (int r = 0; r < 4; ++r) {
            const int co = m * 16 + g4 * 4 + r;
            ob[(size_t)co * (HH * WW)] = a[r] + bias[co];
        }
    }
}

// Fallback (no workspace): round-1 direct-gather kernel (verified, ~146us).
__global__ __launch_bounds__(256) void sphere_conv_fallback(const float* __restrict__ x,
                                                            const float* __restrict__ weight,
                                                            const float* __restrict__ bias,
                                                            const float* __restrict__ grid,
                                                            float* __restrict__ out) {
    __shared__ float wlds[NCIN * 9 * NCOUT];
    const int tid = threadIdx.x;
    for (int e = tid; e < NCIN * 9 * NCOUT; e += 256) {
        const int co  = e & (NCOUT - 1);
        const int cik = e >> 5;
        wlds[e] = weight[co * (NCIN * 9) + cik];
    }
    __syncthreads();

    const int pindex = blockIdx.x * 256 + tid;
    const int c = pindex & (WW - 1);
    const int r = (pindex >> 9) & (HH - 1);
    const int b = pindex >> 17;

    float acc[NCOUT];
#pragma unroll
    for (int o = 0; o < NCOUT; ++o) acc[o] = 0.0f;

    const float2* g2 = reinterpret_cast<const float2*>(grid);

#pragma unroll 1
    for (int k = 0; k < 9; ++k) {
        const int kr = k / 3, kc = k - kr * 3;
        const float2 g = g2[(r * 3 + kr) * (WW * 3) + (c * 3 + kc)];
        const float ix = ((g.x + 1.0f) * 0.5f) * (float)(WW - 1);
        const float iy = ((g.y + 1.0f) * 0.5f) * (float)(HH - 1);
        const float x0f = floorf(ix), y0f = floorf(iy);
        const float fx = ix - x0f, fy = iy - y0f;
        const int x0 = (int)x0f, y0 = (int)y0f;
        const int x1 = x0 + 1, y1 = y0 + 1;
        float wx0 = 1.0f - fx, wx1 = fx, wy0 = 1.0f - fy, wy1 = fy;
        if (x0 < 0 || x0 > WW - 1) wx0 = 0.0f;
        if (x1 < 0 || x1 > WW - 1) wx1 = 0.0f;
        if (y0 < 0 || y0 > HH - 1) wy0 = 0.0f;
        if (y1 < 0 || y1 > HH - 1) wy1 = 0.0f;
        const int cx0 = min(max(x0, 0), WW - 1), cx1 = min(max(x1, 0), WW - 1);
        const int cy0 = min(max(y0, 0), HH - 1), cy1 = min(max(y1, 0), HH - 1);
        const float w00 = wx0 * wy0, w01 = wx1 * wy0, w10 = wx0 * wy1, w11 = wx1 * wy1;

#pragma unroll 1
        for (int ci = 0; ci < NCIN; ++ci) {
            const float* xb = x + (size_t)((b * NCIN + ci) * HH) * WW;
            const float a00 = xb[cy0 * WW + cx0];
            const float a01 = xb[cy0 * WW + cx1];
            const float a10 = xb[cy1 * WW + cx0];
            const float a11 = xb[cy1 * WW + cx1];
            const float s = w00 * a00 + w01 * a01 + w10 * a10 + w11 * a11;
            const float4* wl = reinterpret_cast<const float4*>(&wlds[(ci * 9 + k) * NCOUT]);
#pragma unroll
            for (int o = 0; o < 8; ++o) {
                const float4 wv = wl[o];
                acc[o * 4 + 0] += wv.x * s;
                acc[o * 4 + 1] += wv.y * s;
                acc[o * 4 + 2] += wv.z * s;
                acc[o * 4 + 3] += wv.w * s;
            }
        }
    }

    const int obase = ((b * NCOUT) * HH + r) * WW + c;
#pragma unroll
    for (int o = 0; o < NCOUT; ++o) {
        out[obase + o * (HH * WW)] = acc[o] + bias[o];
    }
}

extern "C" void kernel_launch(void* const* d_in, const int* in_sizes, int n_in,
                              void* d_out, int out_size, void* d_ws, size_t ws_size,
                              hipStream_t stream) {
    const float* x    = (const float*)d_in[0];
    const float* w    = (const float*)d_in[1];
    const float* bias = (const float*)d_in[2];
    const float* grid = (const float*)d_in[3];
    float* out = (float*)d_out;

    if (ws_size >= WS_NEED) {
        char* ws = (char*)d_ws;
        _Float16* xh   = (_Float16*)(ws + XT_OFF);
        float2*   xtab = (float2*)(ws + XTAB_OFF);
        _Float16* wtab = (_Float16*)(ws + WTAB_OFF);
        float4*   ytab = (float4*)(ws + YTAB_OFF);

        precompute_all<<<4638, 256, 0, stream>>>(w, grid, xtab, wtab, ytab);
        transpose_x_kernel<<<2048, 256, 0, stream>>>(x, xh);
        sphere_mfma_kernel<<<8192, 256, 0, stream>>>(xh, xtab, wtab, ytab, bias, out);
    } else {
        sphere_conv_fallback<<<2048, 256, 0, stream>>>(x, w, bias, grid, out);
    }
}

// Round 12
// 56.430 us; speedup vs baseline: 1.5265x; 1.5265x over previous
//
#include <hip/hip_runtime.h>

#define HH 256
#define WW 512
#define NCIN 16
#define NCOUT 32
#define NB 4
#define KP 168     // Sl row stride in halfs (336 B; b128 R/W land on the 8-cyc floor)
#define WKP 168    // wtab row stride in halfs (pad zeroed through 167)
#define NPIX 128   // pixels per block (2 px per lane-pair, 32 px per wave)

typedef _Float16 h2 __attribute__((ext_vector_type(2)));
typedef _Float16 half4 __attribute__((ext_vector_type(4)));
typedef _Float16 half8 __attribute__((ext_vector_type(8)));
typedef float f32x4 __attribute__((ext_vector_type(4)));

// ws layout
#define XT_OFF   0u                  // fp16 xt: 4*256*512*16 half = 16 MiB
#define XTAB_OFF 16777216u           // float2[256*9*512] = 9 MiB
#define WTAB_OFF (16777216u + 9437184u)          // half[32*168]
#define YTAB_OFF (16777216u + 9437184u + 16384u) // float4[256*9]
#define WS_NEED  (YTAB_OFF + 36864u)

// ---- merged precompute: transpose (blocks 0..2047), xtab (2048..6655), wtab/ytab (6656+) ----
__global__ __launch_bounds__(256) void precompute_all(const float* __restrict__ x,
                                                      const float* __restrict__ w,
                                                      const float* __restrict__ grid,
                                                      _Float16* __restrict__ xh,
                                                      float2* __restrict__ xtab,
                                                      _Float16* __restrict__ wtab,
                                                      float4* __restrict__ ytab) {
    const float2* g2 = reinterpret_cast<const float2*>(grid);
    if (blockIdx.x < 2048) {                       // x (B,Cin,H,W) -> xh (B,H,W,Cin) fp16
        const int lb = (blockIdx.x & 7) * 256 + (blockIdx.x >> 3);
        const int t = lb * 256 + threadIdx.x;
        const int c = t & (WW - 1);
        const int r = (t >> 9) & (HH - 1);
        const int b = t >> 17;
        const float* xp = x + ((size_t)(b * NCIN) * HH + r) * WW + c;
        half8 h0, h1;
#pragma unroll
        for (int ci = 0; ci < 8; ++ci)  h0[ci] = (_Float16)xp[(size_t)ci * (HH * WW)];
#pragma unroll
        for (int ci = 0; ci < 8; ++ci)  h1[ci] = (_Float16)xp[(size_t)(8 + ci) * (HH * WW)];
        half8* op = reinterpret_cast<half8*>(xh) + (size_t)t * 2;
        op[0] = h0;
        op[1] = h1;
        return;
    }
    if (blockIdx.x < 2048 + 4608) {                // xtab: {fx, x0} per (r,tap,c)
        const int t = (blockIdx.x - 2048) * 256 + threadIdx.x;
        const int c = t & (WW - 1);
        const int u = t >> 9;
        const int r = u / 9, tap = u - r * 9;
        const int kr = tap / 3, kc = tap - kr * 3;
        const float gx = g2[(size_t)(r * 3 + kr) * (WW * 3) + (c * 3 + kc)].x;
        const float ix = ((gx + 1.0f) * 0.5f) * (float)(WW - 1);
        const float x0f = floorf(ix);
        xtab[t] = make_float2(ix - x0f, __int_as_float((int)x0f));
        return;
    }
    const int t = (blockIdx.x - 6656) * 256 + threadIdx.x;
    if (t < NCOUT * WKP) {                         // wtab, zero-padded rows
        const int co = t / WKP, kk = t - co * WKP;
        float v = 0.0f;
        if (kk < 144) v = w[co * 144 + (kk & 15) * 9 + (kk >> 4)];
        wtab[t] = (_Float16)v;
    } else if (t < NCOUT * WKP + HH * 9) {         // ytab (gy column-independent)
        const int u = t - NCOUT * WKP;
        const int r = u / 9, tap = u - r * 9;
        const int kr = tap / 3, kc = tap - kr * 3;
        const float gy = g2[(size_t)(r * 3 + kr) * (WW * 3) + kc].y;
        const float iy = ((gy + 1.0f) * 0.5f) * (float)(HH - 1);
        const float y0f = floorf(iy);
        const float fy = iy - y0f;
        const int y0 = (int)y0f, y1 = y0 + 1;
        float wy0 = 1.0f - fy, wy1 = fy;
        if (y0 < 0 || y0 > HH - 1) wy0 = 0.0f;
        if (y1 < 0 || y1 > HH - 1) wy1 = 0.0f;
        const int cy0 = min(max(y0, 0), HH - 1), cy1 = min(max(y1, 0), HH - 1);
        ytab[u] = make_float4(wy0, wy1, __int_as_float(cy0), __int_as_float(cy1));
    }
}

// ---- fused sample+conv, round-12 structure: WAVE-INDEPENDENT (no barrier).
// 128 px/block; wave w builds AND consumes px [32w,32w+32). 2 lanes/pixel ->
// half8 (16B) gathers, halving the per-wave load chain vs r11.
__global__ __launch_bounds__(256, 3) void sphere_mfma_kernel(const _Float16* __restrict__ xh,
                                                             const float2* __restrict__ xtab,
                                                             const _Float16* __restrict__ wtab,
                                                             const float4* __restrict__ ytab,
                                                             const float* __restrict__ bias,
                                                             float* __restrict__ out) {
    __shared__ _Float16 Sl[NPIX * KP];   // [px][kk]; wave-private 32-px slabs
    const int tid = threadIdx.x, lane = tid & 63, wv = tid >> 6;
    const int col = lane & 15, g4 = lane >> 4;
    const int pxl = lane >> 1, h = lane & 1;      // build role: pixel-in-wave, channel-half
    const int px = wv * 32 + pxl;                 // block-local pixel 0..127

    const int lb = ((blockIdx.x & 7) << 9) + (blockIdx.x >> 3);  // 4096 blocks, bijective
    const int pixbase = lb << 7;
    const int b    = pixbase >> 17;
    const int rimg = (pixbase >> 9) & (HH - 1);
    const int c0   = pixbase & (WW - 1);

    // zero own Sl pad kk=144..159 (one half8 per lane)
    {
        half8 z = {0, 0, 0, 0, 0, 0, 0, 0};
        *reinterpret_cast<half8*>(&Sl[px * KP + 144 + h * 8]) = z;
    }

    // wave-uniform y-side data (scalar loads); row bases in half8 units
    float wy0s[9], wy1s[9];
    int Rb0[9], Rb1[9];
#pragma unroll
    for (int t = 0; t < 9; ++t) {
        const float4 y = ytab[rimg * 9 + t];
        wy0s[t] = y.x;
        wy1s[t] = y.y;
        Rb0[t] = (b * HH + __float_as_int(y.z)) << 10;
        Rb1[t] = (b * HH + __float_as_int(y.w)) << 10;
    }

    // x-side table loads (per pixel; lane pair shares)
    const float2* xrow = xtab + (size_t)rimg * 9 * WW + (c0 + px);
    float2 f2s[9];
#pragma unroll
    for (int t = 0; t < 9; ++t) f2s[t] = xrow[t * WW];

    // gathers: per tap 4 x half8 (corner pairs share no line; px-adjacent lanes do)
    const half8* x8 = reinterpret_cast<const half8*>(xh);
    half8 A00[9], A01[9], A10[9], A11[9];
#pragma unroll
    for (int t = 0; t < 9; ++t) {
        const int x0 = __float_as_int(f2s[t].y);
        const int pb0 = Rb0[t] + (x0 << 1) + h;
        const int pb1 = Rb1[t] + (x0 << 1) + h;
        A00[t] = x8[pb0];
        A01[t] = x8[pb0 + 2];
        A10[t] = x8[pb1];
        A11[t] = x8[pb1 + 2];
    }

    // interp (packed fp16, per-channel sequence identical to r9-r11) + Sl write
#pragma unroll
    for (int t = 0; t < 9; ++t) {
        const float fx = f2s[t].x;
        const float wx0 = 1.0f - fx;
        const float w00 = wx0 * wy0s[t], w01 = fx * wy0s[t];
        const float w10 = wx0 * wy1s[t], w11 = fx * wy1s[t];
        const _Float16 W00 = (_Float16)w00, W01 = (_Float16)w01;
        const _Float16 W10 = (_Float16)w10, W11 = (_Float16)w11;
        const half8 B00 = {W00, W00, W00, W00, W00, W00, W00, W00};
        const half8 B01 = {W01, W01, W01, W01, W01, W01, W01, W01};
        const half8 B10 = {W10, W10, W10, W10, W10, W10, W10, W10};
        const half8 B11 = {W11, W11, W11, W11, W11, W11, W11, W11};
        half8 pk = A00[t] * B00;
        pk += A01[t] * B01;
        pk += A10[t] * B10;
        pk += A11[t] * B11;
        *reinterpret_cast<half8*>(&Sl[px * KP + t * 16 + h * 8]) = pk;
    }

    // W fragments -> registers (after interp; lifetimes don't overlap A[])
    half8 wA[5][2];
#pragma unroll
    for (int s = 0; s < 5; ++s)
#pragma unroll
        for (int m = 0; m < 2; ++m)
            wA[s][m] = *reinterpret_cast<const half8*>(wtab + (m * 16 + col) * WKP + s * 32 + g4 * 8);

    // NO __syncthreads: wave reads only its own 32-px slab (lgkmcnt orders it)

    // MFMA: wave wv owns px-tiles {2wv, 2wv+1}, couts 0..31
    f32x4 acc[2][2] = {{{0.f, 0.f, 0.f, 0.f}, {0.f, 0.f, 0.f, 0.f}},
                       {{0.f, 0.f, 0.f, 0.f}, {0.f, 0.f, 0.f, 0.f}}};
#pragma unroll
    for (int s = 0; s < 5; ++s)
#pragma unroll
        for (int m = 0; m < 2; ++m) {
            const half8 bf = *reinterpret_cast<const half8*>(
                &Sl[(wv * 32 + m * 16 + col) * KP + s * 32 + g4 * 8]);
            acc[m][0] = __builtin_amdgcn_mfma_f32_16x16x32_f16(wA[s][0], bf, acc[m][0], 0, 0, 0);
            acc[m][1] = __builtin_amdgcn_mfma_f32_16x16x32_f16(wA[s][1], bf, acc[m][1], 0, 0, 0);
        }

    // epilogue: C col=lane&15 (pixel), row=(lane>>4)*4+reg (cout)
#pragma unroll
    for (int m = 0; m < 2; ++m) {
        const int pix = c0 + wv * 32 + m * 16 + col;
        float* ob = out + (((size_t)(b * NCOUT) * HH + rimg) * WW) + pix;
#pragma unroll
        for (int mm = 0; mm < 2; ++mm)
#pragma unroll
            for (int r = 0; r < 4; ++r) {
                const int co = mm * 16 + g4 * 4 + r;
                ob[(size_t)co * (HH * WW)] = acc[m][mm][r] + bias[co];
            }
    }
}

// Fallback (no workspace): round-1 direct-gather kernel (verified, ~146us).
__global__ __launch_bounds__(256) void sphere_conv_fallback(const float* __restrict__ x,
                                                            const float* __restrict__ weight,
                                                            const float* __restrict__ bias,
                                                            const float* __restrict__ grid,
                                                            float* __restrict__ out) {
    __shared__ float wlds[NCIN * 9 * NCOUT];
    const int tid = threadIdx.x;
    for (int e = tid; e < NCIN * 9 * NCOUT; e += 256) {
        const int co  = e & (NCOUT - 1);
        const int cik = e >> 5;
        wlds[e] = weight[co * (NCIN * 9) + cik];
    }
    __syncthreads();

    const int pindex = blockIdx.x * 256 + tid;
    const int c = pindex & (WW - 1);
    const int r = (pindex >> 9) & (HH - 1);
    const int b = pindex >> 17;

    float acc[NCOUT];
#pragma unroll
    for (int o = 0; o < NCOUT; ++o) acc[o] = 0.0f;

    const float2* g2 = reinterpret_cast<const float2*>(grid);

#pragma unroll 1
    for (int k = 0; k < 9; ++k) {
        const int kr = k / 3, kc = k - kr * 3;
        const float2 g = g2[(r * 3 + kr) * (WW * 3) + (c * 3 + kc)];
        const float ix = ((g.x + 1.0f) * 0.5f) * (float)(WW - 1);
        const float iy = ((g.y + 1.0f) * 0.5f) * (float)(HH - 1);
        const float x0f = floorf(ix), y0f = floorf(iy);
        const float fx = ix - x0f, fy = iy - y0f;
        const int x0 = (int)x0f, y0 = (int)y0f;
        const int x1 = x0 + 1, y1 = y0 + 1;
        float wx0 = 1.0f - fx, wx1 = fx, wy0 = 1.0f - fy, wy1 = fy;
        if (x0 < 0 || x0 > WW - 1) wx0 = 0.0f;
        if (x1 < 0 || x1 > WW - 1) wx1 = 0.0f;
        if (y0 < 0 || y0 > HH - 1) wy0 = 0.0f;
        if (y1 < 0 || y1 > HH - 1) wy1 = 0.0f;
        const int cx0 = min(max(x0, 0), WW - 1), cx1 = min(max(x1, 0), WW - 1);
        const int cy0 = min(max(y0, 0), HH - 1), cy1 = min(max(y1, 0), HH - 1);
        const float w00 = wx0 * wy0, w01 = wx1 * wy0, w10 = wx0 * wy1, w11 = wx1 * wy1;

#pragma unroll 1
        for (int ci = 0; ci < NCIN; ++ci) {
            const float* xb = x + (size_t)((b * NCIN + ci) * HH) * WW;
            const float a00 = xb[cy0 * WW + cx0];
            const float a01 = xb[cy0 * WW + cx1];
            const float a10 = xb[cy1 * WW + cx0];
            const float a11 = xb[cy1 * WW + cx1];
            const float s = w00 * a00 + w01 * a01 + w10 * a10 + w11 * a11;
            const float4* wl = reinterpret_cast<const float4*>(&wlds[(ci * 9 + k) * NCOUT]);
#pragma unroll
            for (int o = 0; o < 8; ++o) {
                const float4 wv = wl[o];
                acc[o * 4 + 0] += wv.x * s;
                acc[o * 4 + 1] += wv.y * s;
                acc[o * 4 + 2] += wv.z * s;
                acc[o * 4 + 3] += wv.w * s;
            }
        }
    }

    const int obase = ((b * NCOUT) * HH + r) * WW + c;
#pragma unroll
    for (int o = 0; o < NCOUT; ++o) {
        out[obase + o * (HH * WW)] = acc[o] + bias[o];
    }
}

extern "C" void kernel_launch(void* const* d_in, const int* in_sizes, int n_in,
                              void* d_out, int out_size, void* d_ws, size_t ws_size,
                              hipStream_t stream) {
    const float* x    = (const float*)d_in[0];
    const float* w    = (const float*)d_in[1];
    const float* bias = (const float*)d_in[2];
    const float* grid = (const float*)d_in[3];
    float* out = (float*)d_out;

    if (ws_size >= WS_NEED) {
        char* ws = (char*)d_ws;
        _Float16* xh   = (_Float16*)(ws + XT_OFF);
        float2*   xtab = (float2*)(ws + XTAB_OFF);
        _Float16* wtab = (_Float16*)(ws + WTAB_OFF);
        float4*   ytab = (float4*)(ws + YTAB_OFF);

        precompute_all<<<6686, 256, 0, stream>>>(x, w, grid, xh, xtab, wtab, ytab);
        sphere_mfma_kernel<<<4096, 256, 0, stream>>>(xh, xtab, wtab, ytab, bias, out);
    } else {
        sphere_conv_fallback<<<2048, 256, 0, stream>>>(x, w, bias, grid, out);
    }
}

// Round 13
// 55.584 us; speedup vs baseline: 1.5497x; 1.0152x over previous
//
#include <hip/hip_runtime.h>

#define HH 256
#define WW 512
#define NCIN 16
#define NCOUT 32
#define NB 4
#define KP 152     // Sl row stride in halfs (304 B: 16B-aligned, <=4-way banks)
#define WKP 168    // wtab row stride in halfs (precompute layout unchanged)
#define NPIX 128   // pixels per block (32 px per wave)

typedef _Float16 half4 __attribute__((ext_vector_type(4)));
typedef _Float16 half8 __attribute__((ext_vector_type(8)));
typedef float f32x4 __attribute__((ext_vector_type(4)));
typedef float f32x16 __attribute__((ext_vector_type(16)));

// ws layout
#define XT_OFF   0u                  // fp16 xt: 4*256*512*16 half = 16 MiB
#define XTAB_OFF 16777216u           // float2[256*9*512] = 9 MiB
#define WTAB_OFF (16777216u + 9437184u)          // half[32*168]
#define YTAB_OFF (16777216u + 9437184u + 16384u) // float4[256*9]
#define WS_NEED  (YTAB_OFF + 36864u)

// ---- merged precompute: transpose (blocks 0..2047), xtab (2048..6655), wtab/ytab (6656+) ----
__global__ __launch_bounds__(256) void precompute_all(const float* __restrict__ x,
                                                      const float* __restrict__ w,
                                                      const float* __restrict__ grid,
                                                      _Float16* __restrict__ xh,
                                                      float2* __restrict__ xtab,
                                                      _Float16* __restrict__ wtab,
                                                      float4* __restrict__ ytab) {
    const float2* g2 = reinterpret_cast<const float2*>(grid);
    if (blockIdx.x < 2048) {                       // x (B,Cin,H,W) -> xh (B,H,W,Cin) fp16
        const int lb = (blockIdx.x & 7) * 256 + (blockIdx.x >> 3);
        const int t = lb * 256 + threadIdx.x;
        const int c = t & (WW - 1);
        const int r = (t >> 9) & (HH - 1);
        const int b = t >> 17;
        const float* xp = x + ((size_t)(b * NCIN) * HH + r) * WW + c;
        half8 h0, h1;
#pragma unroll
        for (int ci = 0; ci < 8; ++ci)  h0[ci] = (_Float16)xp[(size_t)ci * (HH * WW)];
#pragma unroll
        for (int ci = 0; ci < 8; ++ci)  h1[ci] = (_Float16)xp[(size_t)(8 + ci) * (HH * WW)];
        half8* op = reinterpret_cast<half8*>(xh) + (size_t)t * 2;
        op[0] = h0;
        op[1] = h1;
        return;
    }
    if (blockIdx.x < 2048 + 4608) {                // xtab: {fx, x0} per (r,tap,c)
        const int t = (blockIdx.x - 2048) * 256 + threadIdx.x;
        const int c = t & (WW - 1);
        const int u = t >> 9;
        const int r = u / 9, tap = u - r * 9;
        const int kr = tap / 3, kc = tap - kr * 3;
        const float gx = g2[(size_t)(r * 3 + kr) * (WW * 3) + (c * 3 + kc)].x;
        const float ix = ((gx + 1.0f) * 0.5f) * (float)(WW - 1);
        const float x0f = floorf(ix);
        xtab[t] = make_float2(ix - x0f, __int_as_float((int)x0f));
        return;
    }
    const int t = (blockIdx.x - 6656) * 256 + threadIdx.x;
    if (t < NCOUT * WKP) {                         // wtab, zero-padded rows
        const int co = t / WKP, kk = t - co * WKP;
        float v = 0.0f;
        if (kk < 144) v = w[co * 144 + (kk & 15) * 9 + (kk >> 4)];
        wtab[t] = (_Float16)v;
    } else if (t < NCOUT * WKP + HH * 9) {         // ytab (gy column-independent)
        const int u = t - NCOUT * WKP;
        const int r = u / 9, tap = u - r * 9;
        const int kr = tap / 3, kc = tap - kr * 3;
        const float gy = g2[(size_t)(r * 3 + kr) * (WW * 3) + kc].y;
        const float iy = ((gy + 1.0f) * 0.5f) * (float)(HH - 1);
        const float y0f = floorf(iy);
        const float fy = iy - y0f;
        const int y0 = (int)y0f, y1 = y0 + 1;
        float wy0 = 1.0f - fy, wy1 = fy;
        if (y0 < 0 || y0 > HH - 1) wy0 = 0.0f;
        if (y1 < 0 || y1 > HH - 1) wy1 = 0.0f;
        const int cy0 = min(max(y0, 0), HH - 1), cy1 = min(max(y1, 0), HH - 1);
        ytab[u] = make_float4(wy0, wy1, __int_as_float(cy0), __int_as_float(cy1));
    }
}

// ---- fused sample+conv, round-13: wave-independent (r12) + per-tap
// mfma_f32_32x32x16_f16 (9 MFMA instead of 20; kk<144 always -> NO K-pad,
// no zero-fill) + KP=152 (LDS 38.9 KB -> 4 blocks/CU).
__global__ __launch_bounds__(256, 4) void sphere_mfma_kernel(const _Float16* __restrict__ xh,
                                                             const float2* __restrict__ xtab,
                                                             const _Float16* __restrict__ wtab,
                                                             const float4* __restrict__ ytab,
                                                             const float* __restrict__ bias,
                                                             float* __restrict__ out) {
    __shared__ _Float16 Sl[NPIX * KP];   // [px][kk], kk = tap*16+ci; wave-private slabs
    const int tid = threadIdx.x, lane = tid & 63, wv = tid >> 6;
    const int c32 = lane & 31, hi = lane >> 5;    // MFMA roles: pixel-in-tile, k-half
    const int pxl = lane >> 1, h = lane & 1;      // build roles: pixel-in-wave, channel-half
    const int px = wv * 32 + pxl;                 // block-local pixel (build)

    const int lb = ((blockIdx.x & 7) << 9) + (blockIdx.x >> 3);  // 4096 blocks, bijective
    const int pixbase = lb << 7;
    const int b    = pixbase >> 17;
    const int rimg = (pixbase >> 9) & (HH - 1);
    const int c0   = pixbase & (WW - 1);

    // wave-uniform y-side data (scalar loads); row bases in half8 units
    float wy0s[9], wy1s[9];
    int Rb0[9], Rb1[9];
#pragma unroll
    for (int t = 0; t < 9; ++t) {
        const float4 y = ytab[rimg * 9 + t];
        wy0s[t] = y.x;
        wy1s[t] = y.y;
        Rb0[t] = (b * HH + __float_as_int(y.z)) << 10;
        Rb1[t] = (b * HH + __float_as_int(y.w)) << 10;
    }

    // x-side table loads (per pixel; lane pair shares)
    const float2* xrow = xtab + (size_t)rimg * 9 * WW + (c0 + px);
    float2 f2s[9];
#pragma unroll
    for (int t = 0; t < 9; ++t) f2s[t] = xrow[t * WW];

    // gathers: per tap 4 x half8 (16B, 2 lanes/pixel)
    const half8* x8 = reinterpret_cast<const half8*>(xh);
    half8 A00[9], A01[9], A10[9], A11[9];
#pragma unroll
    for (int t = 0; t < 9; ++t) {
        const int x0 = __float_as_int(f2s[t].y);
        const int pb0 = Rb0[t] + (x0 << 1) + h;
        const int pb1 = Rb1[t] + (x0 << 1) + h;
        A00[t] = x8[pb0];
        A01[t] = x8[pb0 + 2];
        A10[t] = x8[pb1];
        A11[t] = x8[pb1 + 2];
    }

    // interp (packed fp16, per-channel sequence identical to r12) + Sl write
#pragma unroll
    for (int t = 0; t < 9; ++t) {
        const float fx = f2s[t].x;
        const float wx0 = 1.0f - fx;
        const float w00 = wx0 * wy0s[t], w01 = fx * wy0s[t];
        const float w10 = wx0 * wy1s[t], w11 = fx * wy1s[t];
        const _Float16 W00 = (_Float16)w00, W01 = (_Float16)w01;
        const _Float16 W10 = (_Float16)w10, W11 = (_Float16)w11;
        const half8 B00 = {W00, W00, W00, W00, W00, W00, W00, W00};
        const half8 B01 = {W01, W01, W01, W01, W01, W01, W01, W01};
        const half8 B10 = {W10, W10, W10, W10, W10, W10, W10, W10};
        const half8 B11 = {W11, W11, W11, W11, W11, W11, W11, W11};
        half8 pk = A00[t] * B00;
        pk += A01[t] * B01;
        pk += A10[t] * B10;
        pk += A11[t] * B11;
        *reinterpret_cast<half8*>(&Sl[px * KP + t * 16 + h * 8]) = pk;
    }

    // W fragments -> registers: A row = lane&31 (cout), k = tap*16 + hi*8 + j
    half8 wA[9];
#pragma unroll
    for (int t = 0; t < 9; ++t)
        wA[t] = *reinterpret_cast<const half8*>(wtab + c32 * WKP + t * 16 + hi * 8);

    // NO __syncthreads: wave reads only its own 32-px slab (lgkmcnt orders it)

    // MFMA: one 32x32x16 per tap; B col = lane&31 (pixel), same k mapping
    f32x16 acc = {};
#pragma unroll
    for (int t = 0; t < 9; ++t) {
        const half8 bf = *reinterpret_cast<const half8*>(
            &Sl[(wv * 32 + c32) * KP + t * 16 + hi * 8]);
        acc = __builtin_amdgcn_mfma_f32_32x32x16_f16(wA[t], bf, acc, 0, 0, 0);
    }

    // epilogue: C col=lane&31 (pixel), row=(reg&3)+8*(reg>>2)+4*hi (cout)
    const int pix = c0 + wv * 32 + c32;
    float* ob = out + (((size_t)(b * NCOUT) * HH + rimg) * WW) + pix;
#pragma unroll
    for (int reg = 0; reg < 16; ++reg) {
        const int co = (reg & 3) + 8 * (reg >> 2) + 4 * hi;
        ob[(size_t)co * (HH * WW)] = acc[reg] + bias[co];
    }
}

// Fallback (no workspace): round-1 direct-gather kernel (verified, ~146us).
__global__ __launch_bounds__(256) void sphere_conv_fallback(const float* __restrict__ x,
                                                            const float* __restrict__ weight,
                                                            const float* __restrict__ bias,
                                                            const float* __restrict__ grid,
                                                            float* __restrict__ out) {
    __shared__ float wlds[NCIN * 9 * NCOUT];
    const int tid = threadIdx.x;
    for (int e = tid; e < NCIN * 9 * NCOUT; e += 256) {
        const int co  = e & (NCOUT - 1);
        const int cik = e >> 5;
        wlds[e] = weight[co * (NCIN * 9) + cik];
    }
    __syncthreads();

    const int pindex = blockIdx.x * 256 + tid;
    const int c = pindex & (WW - 1);
    const int r = (pindex >> 9) & (HH - 1);
    const int b = pindex >> 17;

    float acc[NCOUT];
#pragma unroll
    for (int o = 0; o < NCOUT; ++o) acc[o] = 0.0f;

    const float2* g2 = reinterpret_cast<const float2*>(grid);

#pragma unroll 1
    for (int k = 0; k < 9; ++k) {
        const int kr = k / 3, kc = k - kr * 3;
        const float2 g = g2[(r * 3 + kr) * (WW * 3) + (c * 3 + kc)];
        const float ix = ((g.x + 1.0f) * 0.5f) * (float)(WW - 1);
        const float iy = ((g.y + 1.0f) * 0.5f) * (float)(HH - 1);
        const float x0f = floorf(ix), y0f = floorf(iy);
        const float fx = ix - x0f, fy = iy - y0f;
        const int x0 = (int)x0f, y0 = (int)y0f;
        const int x1 = x0 + 1, y1 = y0 + 1;
        float wx0 = 1.0f - fx, wx1 = fx, wy0 = 1.0f - fy, wy1 = fy;
        if (x0 < 0 || x0 > WW - 1) wx0 = 0.0f;
        if (x1 < 0 || x1 > WW - 1) wx1 = 0.0f;
        if (y0 < 0 || y0 > HH - 1) wy0 = 0.0f;
        if (y1 < 0 || y1 > HH - 1) wy1 = 0.0f;
        const int cx0 = min(max(x0, 0), WW - 1), cx1 = min(max(x1, 0), WW - 1);
        const int cy0 = min(max(y0, 0), HH - 1), cy1 = min(max(y1, 0), HH - 1);
        const float w00 = wx0 * wy0, w01 = wx1 * wy0, w10 = wx0 * wy1, w11 = wx1 * wy1;

#pragma unroll 1
        for (int ci = 0; ci < NCIN; ++ci) {
            const float* xb = x + (size_t)((b * NCIN + ci) * HH) * WW;
            const float a00 = xb[cy0 * WW + cx0];
            const float a01 = xb[cy0 * WW + cx1];
            const float a10 = xb[cy1 * WW + cx0];
            const float a11 = xb[cy1 * WW + cx1];
            const float s = w00 * a00 + w01 * a01 + w10 * a10 + w11 * a11;
            const float4* wl = reinterpret_cast<const float4*>(&wlds[(ci * 9 + k) * NCOUT]);
#pragma unroll
            for (int o = 0; o < 8; ++o) {
                const float4 wv = wl[o];
                acc[o * 4 + 0] += wv.x * s;
                acc[o * 4 + 1] += wv.y * s;
                acc[o * 4 + 2] += wv.z * s;
                acc[o * 4 + 3] += wv.w * s;
            }
        }
    }

    const int obase = ((b * NCOUT) * HH + r) * WW + c;
#pragma unroll
    for (int o = 0; o < NCOUT; ++o) {
        out[obase + o * (HH * WW)] = acc[o] + bias[o];
    }
}

extern "C" void kernel_launch(void* const* d_in, const int* in_sizes, int n_in,
                              void* d_out, int out_size, void* d_ws, size_t ws_size,
                              hipStream_t stream) {
    const float* x    = (const float*)d_in[0];
    const float* w    = (const float*)d_in[1];
    const float* bias = (const float*)d_in[2];
    const float* grid = (const float*)d_in[3];
    float* out = (float*)d_out;

    if (ws_size >= WS_NEED) {
        char* ws = (char*)d_ws;
        _Float16* xh   = (_Float16*)(ws + XT_OFF);
        float2*   xtab = (float2*)(ws + XTAB_OFF);
        _Float16* wtab = (_Float16*)(ws + WTAB_OFF);
        float4*   ytab = (float4*)(ws + YTAB_OFF);

        precompute_all<<<6686, 256, 0, stream>>>(x, w, grid, xh, xtab, wtab, ytab);
        sphere_mfma_kernel<<<4096, 256, 0, stream>>>(xh, xtab, wtab, ytab, bias, out);
    } else {
        sphere_conv_fallback<<<2048, 256, 0, stream>>>(x, w, bias, grid, out);
    }
}

// Round 14
// 55.396 us; speedup vs baseline: 1.5549x; 1.0034x over previous
//
#include <hip/hip_runtime.h>

#define HH 256
#define WW 512
#define NCIN 16
#define NCOUT 32
#define NB 4
#define WKP 168    // wtab row stride in halfs

typedef _Float16 half8 __attribute__((ext_vector_type(8)));
typedef float f32x16 __attribute__((ext_vector_type(16)));

// ws layout
#define XT_OFF   0u                  // fp16 xt: 4*256*512*16 half = 16 MiB
#define XTAB_OFF 16777216u           // float2[256*9*512] = 9 MiB
#define WTAB_OFF (16777216u + 9437184u)          // half[32*168]
#define YTAB_OFF (16777216u + 9437184u + 16384u) // float4[256*9]
#define WS_NEED  (YTAB_OFF + 36864u)

// ---- merged precompute: transpose (blocks 0..2047), xtab (2048..6655), wtab/ytab (6656+) ----
__global__ __launch_bounds__(256) void precompute_all(const float* __restrict__ x,
                                                      const float* __restrict__ w,
                                                      const float* __restrict__ grid,
                                                      _Float16* __restrict__ xh,
                                                      float2* __restrict__ xtab,
                                                      _Float16* __restrict__ wtab,
                                                      float4* __restrict__ ytab) {
    const float2* g2 = reinterpret_cast<const float2*>(grid);
    if (blockIdx.x < 2048) {                       // x (B,Cin,H,W) -> xh (B,H,W,Cin) fp16
        const int lb = (blockIdx.x & 7) * 256 + (blockIdx.x >> 3);
        const int t = lb * 256 + threadIdx.x;
        const int c = t & (WW - 1);
        const int r = (t >> 9) & (HH - 1);
        const int b = t >> 17;
        const float* xp = x + ((size_t)(b * NCIN) * HH + r) * WW + c;
        half8 h0, h1;
#pragma unroll
        for (int ci = 0; ci < 8; ++ci)  h0[ci] = (_Float16)xp[(size_t)ci * (HH * WW)];
#pragma unroll
        for (int ci = 0; ci < 8; ++ci)  h1[ci] = (_Float16)xp[(size_t)(8 + ci) * (HH * WW)];
        half8* op = reinterpret_cast<half8*>(xh) + (size_t)t * 2;
        op[0] = h0;
        op[1] = h1;
        return;
    }
    if (blockIdx.x < 2048 + 4608) {                // xtab: {fx, x0} per (r,tap,c)
        const int t = (blockIdx.x - 2048) * 256 + threadIdx.x;
        const int c = t & (WW - 1);
        const int u = t >> 9;
        const int r = u / 9, tap = u - r * 9;
        const int kr = tap / 3, kc = tap - kr * 3;
        const float gx = g2[(size_t)(r * 3 + kr) * (WW * 3) + (c * 3 + kc)].x;
        const float ix = ((gx + 1.0f) * 0.5f) * (float)(WW - 1);
        const float x0f = floorf(ix);
        xtab[t] = make_float2(ix - x0f, __int_as_float((int)x0f));
        return;
    }
    const int t = (blockIdx.x - 6656) * 256 + threadIdx.x;
    if (t < NCOUT * WKP) {                         // wtab, zero-padded rows
        const int co = t / WKP, kk = t - co * WKP;
        float v = 0.0f;
        if (kk < 144) v = w[co * 144 + (kk & 15) * 9 + (kk >> 4)];
        wtab[t] = (_Float16)v;
    } else if (t < NCOUT * WKP + HH * 9) {         // ytab (gy column-independent)
        const int u = t - NCOUT * WKP;
        const int r = u / 9, tap = u - r * 9;
        const int kr = tap / 3, kc = tap - kr * 3;
        const float gy = g2[(size_t)(r * 3 + kr) * (WW * 3) + kc].y;
        const float iy = ((gy + 1.0f) * 0.5f) * (float)(HH - 1);
        const float y0f = floorf(iy);
        const float fy = iy - y0f;
        const int y0 = (int)y0f, y1 = y0 + 1;
        float wy0 = 1.0f - fy, wy1 = fy;
        if (y0 < 0 || y0 > HH - 1) wy0 = 0.0f;
        if (y1 < 0 || y1 > HH - 1) wy1 = 0.0f;
        const int cy0 = min(max(y0, 0), HH - 1), cy1 = min(max(y1, 0), HH - 1);
        ytab[u] = make_float4(wy0, wy1, __int_as_float(cy0), __int_as_float(cy1));
    }
}

// ---- fused sample+conv, round-14: ZERO-LDS. Build roles = MFMA B-fragment
// roles (px = lane&31, h = lane>>5), so the interpolated half8 IS the
// 32x32x16 B operand in registers. All LDS staging deleted (r13's 36 ds ops
// were a pure layout conversion). Wave-independent, no barrier.
__global__ __launch_bounds__(256, 4) void sphere_mfma_kernel(const _Float16* __restrict__ xh,
                                                             const float2* __restrict__ xtab,
                                                             const _Float16* __restrict__ wtab,
                                                             const float4* __restrict__ ytab,
                                                             const float* __restrict__ bias,
                                                             float* __restrict__ out) {
    const int tid = threadIdx.x, lane = tid & 63, wv = tid >> 6;
    const int c32 = lane & 31, h = lane >> 5;     // pixel-in-tile, channel-half (build==MFMA)
    const int px = wv * 32 + c32;                 // block-local pixel

    const int lb = ((blockIdx.x & 7) << 9) + (blockIdx.x >> 3);  // 4096 blocks, bijective
    const int pixbase = lb << 7;
    const int b    = pixbase >> 17;
    const int rimg = (pixbase >> 9) & (HH - 1);
    const int c0   = pixbase & (WW - 1);

    // wave-uniform y-side data (scalar loads); row bases in half8 units
    float wy0s[9], wy1s[9];
    int Rb0[9], Rb1[9];
#pragma unroll
    for (int t = 0; t < 9; ++t) {
        const float4 y = ytab[rimg * 9 + t];
        wy0s[t] = y.x;
        wy1s[t] = y.y;
        Rb0[t] = (b * HH + __float_as_int(y.z)) << 10;
        Rb1[t] = (b * HH + __float_as_int(y.w)) << 10;
    }

    // x-side table loads (per pixel; h=0/1 half-waves read the same values)
    const float2* xrow = xtab + (size_t)rimg * 9 * WW + (c0 + px);
    float2 f2s[9];
#pragma unroll
    for (int t = 0; t < 9; ++t) f2s[t] = xrow[t * WW];

    // W fragments: A row = lane&31 (cout), k = tap*16 + h*8 + j  (L2-hot)
    half8 wA[9];
#pragma unroll
    for (int t = 0; t < 9; ++t)
        wA[t] = *reinterpret_cast<const half8*>(wtab + c32 * WKP + t * 16 + h * 8);

    // gathers + interp + MFMA, all in registers; pk IS the B-fragment
    const half8* x8 = reinterpret_cast<const half8*>(xh);
    f32x16 acc = {};
#pragma unroll
    for (int t = 0; t < 9; ++t) {
        const int x0 = __float_as_int(f2s[t].y);
        const int pb0 = Rb0[t] + (x0 << 1) + h;
        const int pb1 = Rb1[t] + (x0 << 1) + h;
        const half8 A00 = x8[pb0];
        const half8 A01 = x8[pb0 + 2];
        const half8 A10 = x8[pb1];
        const half8 A11 = x8[pb1 + 2];

        const float fx = f2s[t].x;
        const float wx0 = 1.0f - fx;
        const float w00 = wx0 * wy0s[t], w01 = fx * wy0s[t];
        const float w10 = wx0 * wy1s[t], w11 = fx * wy1s[t];
        const _Float16 W00 = (_Float16)w00, W01 = (_Float16)w01;
        const _Float16 W10 = (_Float16)w10, W11 = (_Float16)w11;
        const half8 B00 = {W00, W00, W00, W00, W00, W00, W00, W00};
        const half8 B01 = {W01, W01, W01, W01, W01, W01, W01, W01};
        const half8 B10 = {W10, W10, W10, W10, W10, W10, W10, W10};
        const half8 B11 = {W11, W11, W11, W11, W11, W11, W11, W11};
        half8 pk = A00 * B00;
        pk += A01 * B01;
        pk += A10 * B10;
        pk += A11 * B11;

        acc = __builtin_amdgcn_mfma_f32_32x32x16_f16(wA[t], pk, acc, 0, 0, 0);
    }

    // epilogue: C col=lane&31 (pixel), row=(reg&3)+8*(reg>>2)+4*h (cout)
    const int pix = c0 + wv * 32 + c32;
    float* ob = out + (((size_t)(b * NCOUT) * HH + rimg) * WW) + pix;
#pragma unroll
    for (int reg = 0; reg < 16; ++reg) {
        const int co = (reg & 3) + 8 * (reg >> 2) + 4 * h;
        ob[(size_t)co * (HH * WW)] = acc[reg] + bias[co];
    }
}

// Fallback (no workspace): round-1 direct-gather kernel (verified, ~146us).
__global__ __launch_bounds__(256) void sphere_conv_fallback(const float* __restrict__ x,
                                                            const float* __restrict__ weight,
                                                            const float* __restrict__ bias,
                                                            const float* __restrict__ grid,
                                                            float* __restrict__ out) {
    __shared__ float wlds[NCIN * 9 * NCOUT];
    const int tid = threadIdx.x;
    for (int e = tid; e < NCIN * 9 * NCOUT; e += 256) {
        const int co  = e & (NCOUT - 1);
        const int cik = e >> 5;
        wlds[e] = weight[co * (NCIN * 9) + cik];
    }
    __syncthreads();

    const int pindex = blockIdx.x * 256 + tid;
    const int c = pindex & (WW - 1);
    const int r = (pindex >> 9) & (HH - 1);
    const int b = pindex >> 17;

    float acc[NCOUT];
#pragma unroll
    for (int o = 0; o < NCOUT; ++o) acc[o] = 0.0f;

    const float2* g2 = reinterpret_cast<const float2*>(grid);

#pragma unroll 1
    for (int k = 0; k < 9; ++k) {
        const int kr = k / 3, kc = k - kr * 3;
        const float2 g = g2[(r * 3 + kr) * (WW * 3) + (c * 3 + kc)];
        const float ix = ((g.x + 1.0f) * 0.5f) * (float)(WW - 1);
        const float iy = ((g.y + 1.0f) * 0.5f) * (float)(HH - 1);
        const float x0f = floorf(ix), y0f = floorf(iy);
        const float fx = ix - x0f, fy = iy - y0f;
        const int x0 = (int)x0f, y0 = (int)y0f;
        const int x1 = x0 + 1, y1 = y0 + 1;
        float wx0 = 1.0f - fx, wx1 = fx, wy0 = 1.0f - fy, wy1 = fy;
        if (x0 < 0 || x0 > WW - 1) wx0 = 0.0f;
        if (x1 < 0 || x1 > WW - 1) wx1 = 0.0f;
        if (y0 < 0 || y0 > HH - 1) wy0 = 0.0f;
        if (y1 < 0 || y1 > HH - 1) wy1 = 0.0f;
        const int cx0 = min(max(x0, 0), WW - 1), cx1 = min(max(x1, 0), WW - 1);
        const int cy0 = min(max(y0, 0), HH - 1), cy1 = min(max(y1, 0), HH - 1);
        const float w00 = wx0 * wy0, w01 = wx1 * wy0, w10 = wx0 * wy1, w11 = wx1 * wy1;

#pragma unroll 1
        for (int ci = 0; ci < NCIN; ++ci) {
            const float* xb = x + (size_t)((b * NCIN + ci) * HH) * WW;
            const float a00 = xb[cy0 * WW + cx0];
            const float a01 = xb[cy0 * WW + cx1];
            const float a10 = xb[cy1 * WW + cx0];
            const float a11 = xb[cy1 * WW + cx1];
            const float s = w00 * a00 + w01 * a01 + w10 * a10 + w11 * a11;
            const float4* wl = reinterpret_cast<const float4*>(&wlds[(ci * 9 + k) * NCOUT]);
#pragma unroll
            for (int o = 0; o < 8; ++o) {
                const float4 wv = wl[o];
                acc[o * 4 + 0] += wv.x * s;
                acc[o * 4 + 1] += wv.y * s;
                acc[o * 4 + 2] += wv.z * s;
                acc[o * 4 + 3] += wv.w * s;
            }
        }
    }

    const int obase = ((b * NCOUT) * HH + r) * WW + c;
#pragma unroll
    for (int o = 0; o < NCOUT; ++o) {
        out[obase + o * (HH * WW)] = acc[o] + bias[o];
    }
}

extern "C" void kernel_launch(void* const* d_in, const int* in_sizes, int n_in,
                              void* d_out, int out_size, void* d_ws, size_t ws_size,
                              hipStream_t stream) {
    const float* x    = (const float*)d_in[0];
    const float* w    = (const float*)d_in[1];
    const float* bias = (const float*)d_in[2];
    const float* grid = (const float*)d_in[3];
    float* out = (float*)d_out;

    if (ws_size >= WS_NEED) {
        char* ws = (char*)d_ws;
        _Float16* xh   = (_Float16*)(ws + XT_OFF);
        float2*   xtab = (float2*)(ws + XTAB_OFF);
        _Float16* wtab = (_Float16*)(ws + WTAB_OFF);
        float4*   ytab = (float4*)(ws + YTAB_OFF);

        precompute_all<<<6686, 256, 0, stream>>>(x, w, grid, xh, xtab, wtab, ytab);
        sphere_mfma_kernel<<<4096, 256, 0, stream>>>(xh, xtab, wtab, ytab, bias, out);
    } else {
        sphere_conv_fallback<<<2048, 256, 0, stream>>>(x, w, bias, grid, out);
    }
}

// Round 15
// 49.782 us; speedup vs baseline: 1.7303x; 1.1128x over previous
//
#include <hip/hip_runtime.h>

#define HH 256
#define WW 512
#define NCIN 16
#define NCOUT 32
#define NB 4

typedef _Float16 half8 __attribute__((ext_vector_type(8)));
typedef float f32x16 __attribute__((ext_vector_type(16)));

// ws layout
#define XT_OFF   0u                  // fp16 xt: 4*256*512*16 half = 16 MiB
#define XTAB_OFF 16777216u           // float2[256*9*512] = 9 MiB
#define WFRAG_OFF (16777216u + 9437184u)          // half[9*64*8] = 9216 B
#define YTAB_OFF (16777216u + 9437184u + 16384u)  // float4[256*9]
#define WS_NEED  (YTAB_OFF + 36864u)

// ---- merged precompute ----
// blocks [0,2048): x (B,Cin,H,W) -> xh (B,H,W,Cin) fp16
// blocks [2048,6656): xtab {fx,x0}, COALESCED grid reads (thread = raw grid elem)
// blocks [6656,6674): wfrag — weights in per-lane MFMA A-fragment order
// blocks [6674,6683): ytab (gy column-independent)
__global__ __launch_bounds__(256) void precompute_all(const float* __restrict__ x,
                                                      const float* __restrict__ w,
                                                      const float* __restrict__ grid,
                                                      _Float16* __restrict__ xh,
                                                      float2* __restrict__ xtab,
                                                      _Float16* __restrict__ wfrag,
                                                      float4* __restrict__ ytab) {
    const float2* g2 = reinterpret_cast<const float2*>(grid);
    if (blockIdx.x < 2048) {
        const int lb = (blockIdx.x & 7) * 256 + (blockIdx.x >> 3);
        const int t = lb * 256 + threadIdx.x;
        const int c = t & (WW - 1);
        const int r = (t >> 9) & (HH - 1);
        const int b = t >> 17;
        const float* xp = x + ((size_t)(b * NCIN) * HH + r) * WW + c;
        half8 h0, h1;
#pragma unroll
        for (int ci = 0; ci < 8; ++ci)  h0[ci] = (_Float16)xp[(size_t)ci * (HH * WW)];
#pragma unroll
        for (int ci = 0; ci < 8; ++ci)  h1[ci] = (_Float16)xp[(size_t)(8 + ci) * (HH * WW)];
        half8* op = reinterpret_cast<half8*>(xh) + (size_t)t * 2;
        op[0] = h0;
        op[1] = h1;
        return;
    }
    if (blockIdx.x < 6656) {                       // xtab, coalesced
        const int T = (blockIdx.x - 2048) * 256 + threadIdx.x;   // 0 .. 768*1536-1
        const int gr = T / 1536, j = T - gr * 1536;   // grid row, col3
        const int r = gr / 3, kr = gr - r * 3;
        const int c = j / 3, kc = j - c * 3;
        const float gx = g2[(size_t)gr * 1536 + j].x;             // stride-1 read
        const float ix = ((gx + 1.0f) * 0.5f) * (float)(WW - 1);
        const float x0f = floorf(ix);
        xtab[(size_t)(r * 9 + kr * 3 + kc) * WW + c] = make_float2(ix - x0f, __int_as_float((int)x0f));
        return;
    }
    if (blockIdx.x < 6674) {                       // wfrag[t][lane][j]
        const int e = (blockIdx.x - 6656) * 256 + threadIdx.x;    // 0..4607
        const int j = e & 7, lane = (e >> 3) & 63, t = e >> 9;
        const int c32 = lane & 31, h = lane >> 5;
        wfrag[e] = (_Float16)w[c32 * 144 + (h * 8 + j) * 9 + t];
        return;
    }
    const int u = (blockIdx.x - 6674) * 256 + threadIdx.x;        // 0..2303
    if (u < HH * 9) {
        const int r = u / 9, tap = u - r * 9;
        const int kr = tap / 3, kc = tap - kr * 3;
        const float gy = g2[(size_t)(r * 3 + kr) * 1536 + kc].y;
        const float iy = ((gy + 1.0f) * 0.5f) * (float)(HH - 1);
        const float y0f = floorf(iy);
        const float fy = iy - y0f;
        const int y0 = (int)y0f, y1 = y0 + 1;
        float wy0 = 1.0f - fy, wy1 = fy;
        if (y0 < 0 || y0 > HH - 1) wy0 = 0.0f;
        if (y1 < 0 || y1 > HH - 1) wy1 = 0.0f;
        const int cy0 = min(max(y0, 0), HH - 1), cy1 = min(max(y1, 0), HH - 1);
        ytab[u] = make_float4(wy0, wy1, __int_as_float(cy0), __int_as_float(cy1));
    }
}

// ---- fused sample+conv, round-15: zero-LDS (r14) + coalesced fragment-order
// weight loads (wtab strided reads were ~1150 lines/block = 29% of TA traffic)
// + depth-2 gather pipeline (rotating a/b buffers).
__global__ __launch_bounds__(256, 4) void sphere_mfma_kernel(const _Float16* __restrict__ xh,
                                                             const float2* __restrict__ xtab,
                                                             const _Float16* __restrict__ wfrag,
                                                             const float4* __restrict__ ytab,
                                                             const float* __restrict__ bias,
                                                             float* __restrict__ out) {
    const int tid = threadIdx.x, lane = tid & 63, wv = tid >> 6;
    const int c32 = lane & 31, h = lane >> 5;     // pixel-in-tile, channel-half
    const int px = wv * 32 + c32;                 // block-local pixel

    const int lb = ((blockIdx.x & 7) << 9) + (blockIdx.x >> 3);  // 4096 blocks, bijective
    const int pixbase = lb << 7;
    const int b    = pixbase >> 17;
    const int rimg = (pixbase >> 9) & (HH - 1);
    const int c0   = pixbase & (WW - 1);

    // wave-uniform y-side data; row bases in half8 units
    float wy0s[9], wy1s[9];
    int Rb0[9], Rb1[9];
#pragma unroll
    for (int t = 0; t < 9; ++t) {
        const float4 y = ytab[rimg * 9 + t];
        wy0s[t] = y.x;
        wy1s[t] = y.y;
        Rb0[t] = (b * HH + __float_as_int(y.z)) << 10;
        Rb1[t] = (b * HH + __float_as_int(y.w)) << 10;
    }

    // x-side table loads (per pixel)
    const float2* xrow = xtab + (size_t)rimg * 9 * WW + (c0 + px);
    float2 f2s[9];
#pragma unroll
    for (int t = 0; t < 9; ++t) f2s[t] = xrow[t * WW];

    // W fragments, fragment-ordered -> 9 fully-coalesced 16B loads
    const half8* wf8 = reinterpret_cast<const half8*>(wfrag);
    half8 wA[9];
#pragma unroll
    for (int t = 0; t < 9; ++t) wA[t] = wf8[t * 64 + lane];

    const half8* x8 = reinterpret_cast<const half8*>(xh);
    f32x16 acc = {};

    half8 A00a, A01a, A10a, A11a, A00b, A01b, A10b, A11b;

#define GLOAD(tt, S)                                                     \
    {                                                                    \
        const int x0_ = __float_as_int(f2s[tt].y);                       \
        const int p0_ = Rb0[tt] + (x0_ << 1) + h;                        \
        const int p1_ = Rb1[tt] + (x0_ << 1) + h;                        \
        A00##S = x8[p0_];                                                \
        A01##S = x8[p0_ + 2];                                            \
        A10##S = x8[p1_];                                                \
        A11##S = x8[p1_ + 2];                                            \
    }

#define CONSUME(tt, S)                                                   \
    {                                                                    \
        const float fx_ = f2s[tt].x;                                     \
        const float wx0_ = 1.0f - fx_;                                   \
        const float w00_ = wx0_ * wy0s[tt], w01_ = fx_ * wy0s[tt];       \
        const float w10_ = wx0_ * wy1s[tt], w11_ = fx_ * wy1s[tt];       \
        const _Float16 W00_ = (_Float16)w00_, W01_ = (_Float16)w01_;     \
        const _Float16 W10_ = (_Float16)w10_, W11_ = (_Float16)w11_;     \
        const half8 B00_ = {W00_, W00_, W00_, W00_, W00_, W00_, W00_, W00_}; \
        const half8 B01_ = {W01_, W01_, W01_, W01_, W01_, W01_, W01_, W01_}; \
        const half8 B10_ = {W10_, W10_, W10_, W10_, W10_, W10_, W10_, W10_}; \
        const half8 B11_ = {W11_, W11_, W11_, W11_, W11_, W11_, W11_, W11_}; \
        half8 pk_ = A00##S * B00_;                                       \
        pk_ += A01##S * B01_;                                            \
        pk_ += A10##S * B10_;                                            \
        pk_ += A11##S * B11_;                                            \
        acc = __builtin_amdgcn_mfma_f32_32x32x16_f16(wA[tt], pk_, acc, 0, 0, 0); \
    }

    // depth-2 software pipeline over taps
    GLOAD(0, a)
    GLOAD(1, b)
    CONSUME(0, a) GLOAD(2, a)
    CONSUME(1, b) GLOAD(3, b)
    CONSUME(2, a) GLOAD(4, a)
    CONSUME(3, b) GLOAD(5, b)
    CONSUME(4, a) GLOAD(6, a)
    CONSUME(5, b) GLOAD(7, b)
    CONSUME(6, a) GLOAD(8, a)
    CONSUME(7, b)
    CONSUME(8, a)
#undef GLOAD
#undef CONSUME

    // epilogue: C col=lane&31 (pixel), row=(reg&3)+8*(reg>>2)+4*h (cout)
    const int pix = c0 + wv * 32 + c32;
    float* ob = out + (((size_t)(b * NCOUT) * HH + rimg) * WW) + pix;
#pragma unroll
    for (int reg = 0; reg < 16; ++reg) {
        const int co = (reg & 3) + 8 * (reg >> 2) + 4 * h;
        ob[(size_t)co * (HH * WW)] = acc[reg] + bias[co];
    }
}

// Fallback (no workspace): round-1 direct-gather kernel (verified, ~146us).
__global__ __launch_bounds__(256) void sphere_conv_fallback(const float* __restrict__ x,
                                                            const float* __restrict__ weight,
                                                            const float* __restrict__ bias,
                                                            const float* __restrict__ grid,
                                                            float* __restrict__ out) {
    __shared__ float wlds[NCIN * 9 * NCOUT];
    const int tid = threadIdx.x;
    for (int e = tid; e < NCIN * 9 * NCOUT; e += 256) {
        const int co  = e & (NCOUT - 1);
        const int cik = e >> 5;
        wlds[e] = weight[co * (NCIN * 9) + cik];
    }
    __syncthreads();

    const int pindex = blockIdx.x * 256 + tid;
    const int c = pindex & (WW - 1);
    const int r = (pindex >> 9) & (HH - 1);
    const int b = pindex >> 17;

    float acc[NCOUT];
#pragma unroll
    for (int o = 0; o < NCOUT; ++o) acc[o] = 0.0f;

    const float2* g2 = reinterpret_cast<const float2*>(grid);

#pragma unroll 1
    for (int k = 0; k < 9; ++k) {
        const int kr = k / 3, kc = k - kr * 3;
        const float2 g = g2[(r * 3 + kr) * (WW * 3) + (c * 3 + kc)];
        const float ix = ((g.x + 1.0f) * 0.5f) * (float)(WW - 1);
        const float iy = ((g.y + 1.0f) * 0.5f) * (float)(HH - 1);
        const float x0f = floorf(ix), y0f = floorf(iy);
        const float fx = ix - x0f, fy = iy - y0f;
        const int x0 = (int)x0f, y0 = (int)y0f;
        const int x1 = x0 + 1, y1 = y0 + 1;
        float wx0 = 1.0f - fx, wx1 = fx, wy0 = 1.0f - fy, wy1 = fy;
        if (x0 < 0 || x0 > WW - 1) wx0 = 0.0f;
        if (x1 < 0 || x1 > WW - 1) wx1 = 0.0f;
        if (y0 < 0 || y0 > HH - 1) wy0 = 0.0f;
        if (y1 < 0 || y1 > HH - 1) wy1 = 0.0f;
        const int cx0 = min(max(x0, 0), WW - 1), cx1 = min(max(x1, 0), WW - 1);
        const int cy0 = min(max(y0, 0), HH - 1), cy1 = min(max(y1, 0), HH - 1);
        const float w00 = wx0 * wy0, w01 = wx1 * wy0, w10 = wx0 * wy1, w11 = wx1 * wy1;

#pragma unroll 1
        for (int ci = 0; ci < NCIN; ++ci) {
            const float* xb = x + (size_t)((b * NCIN + ci) * HH) * WW;
            const float a00 = xb[cy0 * WW + cx0];
            const float a01 = xb[cy0 * WW + cx1];
            const float a10 = xb[cy1 * WW + cx0];
            const float a11 = xb[cy1 * WW + cx1];
            const float s = w00 * a00 + w01 * a01 + w10 * a10 + w11 * a11;
            const float4* wl = reinterpret_cast<const float4*>(&wlds[(ci * 9 + k) * NCOUT]);
#pragma unroll
            for (int o = 0; o < 8; ++o) {
                const float4 wv = wl[o];
                acc[o * 4 + 0] += wv.x * s;
                acc[o * 4 + 1] += wv.y * s;
                acc[o * 4 + 2] += wv.z * s;
                acc[o * 4 + 3] += wv.w * s;
            }
        }
    }

    const int obase = ((b * NCOUT) * HH + r) * WW + c;
#pragma unroll
    for (int o = 0; o < NCOUT; ++o) {
        out[obase + o * (HH * WW)] = acc[o] + bias[o];
    }
}

extern "C" void kernel_launch(void* const* d_in, const int* in_sizes, int n_in,
                              void* d_out, int out_size, void* d_ws, size_t ws_size,
                              hipStream_t stream) {
    const float* x    = (const float*)d_in[0];
    const float* w    = (const float*)d_in[1];
    const float* bias = (const float*)d_in[2];
    const float* grid = (const float*)d_in[3];
    float* out = (float*)d_out;

    if (ws_size >= WS_NEED) {
        char* ws = (char*)d_ws;
        _Float16* xh    = (_Float16*)(ws + XT_OFF);
        float2*   xtab  = (float2*)(ws + XTAB_OFF);
        _Float16* wfrag = (_Float16*)(ws + WFRAG_OFF);
        float4*   ytab  = (float4*)(ws + YTAB_OFF);

        precompute_all<<<6683, 256, 0, stream>>>(x, w, grid, xh, xtab, wfrag, ytab);
        sphere_mfma_kernel<<<4096, 256, 0, stream>>>(xh, xtab, wfrag, ytab, bias, out);
    } else {
        sphere_conv_fallback<<<2048, 256, 0, stream>>>(x, w, bias, grid, out);
    }
}